// Round 8
// baseline (241.200 us; speedup 1.0000x reference)
//
#include <hip/hip_runtime.h>
#include <hip/hip_bf16.h>

// MQA fused pipeline, bf16 MFMA (32x32x16), fp32 accumulate.
// B=2, L=2048, D_MODEL=2048, H=16, HD=128.
// HARNESS DTYPES (established r1-r3): inputs fp32, OUTPUT fp32
// (threshold bf16-calibrated 3.6e-3).
//
// R13 post-mortem (FAILED, attn 80.7): halving LDS reads didn't help; with
// R12 (barriers) and R9/R11 (VALU) also null/negative, R8's attn (73.2us,
// MfmaUtil 40 + VALUBusy 35) is a packed local optimum. attn FROZEN at exact
// R8 below.
// Cross-round accounting: totals stable at 232-236 while attn wobbles ->
// gemm is ~60-73us (hidden under attn in top-5; R8 rebuild barely beat the
// original 88), convert ~13, fixed overhead ~55-70. Gemm arithmetic: per
// CU-iter ds_read 1536 + LDS-write 576 > MFMA 1034 cyc -> LDS-pipe-bound at
// 1:1 read:MFMA.
// R14: rebuild Q-projection as 256x256-tile / 4 waves / 4x4 acc per wave
// (wave tile 128x128): per kc 8 reads -> 16 MFMAs (1:2), per-CU LDS ~2112 vs
// MFMA ~2066 (balanced). 147KB LDS dbuf, 1 block/CU, same 1-barrier schedule,
// same staging/fragment/epilogue maps (same accumulation order -> bitwise-
// identical Q). K/V keep the old verified 128^2 path in the same kernel
// (own 18432-u16 buffer stride). Grid 128 Q + 64 K/V = 192 blocks, no tail.
// Predicted: attn ~73-74, gemm ~40-50 (below top-5), total ~200-212.
//
// ws layout (bytes):
//   xb   @ 0         : x   bf16 [4096][2048]   16777216
//   wqb  @ 16777216  : Wq  bf16 [2048][2048]    8388608
//   wkb  @ 25165824  : Wk  bf16 [128][2048]      524288
//   wvb  @ 25690112  : Wv  bf16 [128][2048]      524288
//   qb   @ 26214400  : Q   bf16 [4096][2048]   16777216  (pre-scaled log2e/sqrt(128))
//   kbuf @ 42991616  : K   bf16 [4096][128]     1048576
//   vtb  @ 44040192  : V^T bf16 [2][128][2048]  1048576
// total 45088768

typedef unsigned short u16;
typedef unsigned int u32;
typedef __bf16 bf16x8 __attribute__((ext_vector_type(8)));
typedef float f32x16 __attribute__((ext_vector_type(16)));
typedef u16 u16x4 __attribute__((ext_vector_type(4)));
typedef u32 u32x4 __attribute__((ext_vector_type(4)));

#define MFMA32(a, b, c) __builtin_amdgcn_mfma_f32_32x32x16_bf16((a), (b), (c), 0, 0, 0)

__device__ __forceinline__ u16 f2bf(float f) {
  __hip_bfloat16 h = __float2bfloat16(f);
  return __builtin_bit_cast(u16, h);
}

__device__ __forceinline__ float fexp2(float x) {
#if __has_builtin(__builtin_amdgcn_exp2f)
  return __builtin_amdgcn_exp2f(x);
#else
  return exp2f(x);
#endif
}

// async global->LDS, 16B per lane; LDS dest = wave-uniform base + lane*16
__device__ __forceinline__ void cp16(const void* g, void* l) {
  __builtin_amdgcn_global_load_lds(
      (const __attribute__((address_space(1))) u32*)g,
      (__attribute__((address_space(3))) u32*)l, 16, 0, 0);
}

__device__ __forceinline__ f32x16 zero16() {
  f32x16 v;
#pragma unroll
  for (int i = 0; i < 16; ++i) v[i] = 0.f;
  return v;
}

// ---------------------------------------------------------------- K1: convert
__global__ __launch_bounds__(256) void k_convert(
    const float* __restrict__ x, const float* __restrict__ wq,
    const float* __restrict__ wk, const float* __restrict__ wv,
    u16* __restrict__ xb, u16* __restrict__ wqb,
    u16* __restrict__ wkb, u16* __restrict__ wvb) {
  int idx = blockIdx.x * 256 + threadIdx.x;
  // float4 counts: x 2097152 | wq 1048576 | wk 65536 | wv 65536 = 3276800
  for (int i = idx; i < 3276800; i += 524288) {
    float4 v; u16* dst;
    if (i < 2097152) {
      v = ((const float4*)x)[i]; dst = xb + (size_t)i * 4;
    } else if (i < 3145728) {
      int j = i - 2097152; v = ((const float4*)wq)[j]; dst = wqb + (size_t)j * 4;
    } else if (i < 3211264) {
      int j = i - 3145728; v = ((const float4*)wk)[j]; dst = wkb + (size_t)j * 4;
    } else {
      int j = i - 3211264; v = ((const float4*)wv)[j]; dst = wvb + (size_t)j * 4;
    }
    u16x4 o;
    o[0] = f2bf(v.x); o[1] = f2bf(v.y); o[2] = f2bf(v.z); o[3] = f2bf(v.w);
    *(u16x4*)dst = o;
  }
}

// ------------------------------------------------- K2: Q and K/V^T projections
// 1D grid of 192 blocks, 256 thr:
//  id < 128 -> Q, 256x256 tile (m0=(id>>3)*256, n0=(id&7)*256), 4x4 acc/wave,
//    LDS As[256][72] @0 | Bs[256][72] @18432 u16, dbuf stride 36864 u16.
//  id >= 128 -> K (id<160) / V (else), old 128x128 tile path, dbuf stride
//    18432 u16 (uses only the front of the allocation).
// Both: BK=64, 1 barrier/iter dbuf, rows padded to 72 u16 (9x16B slots, pad
// slot in the async-copy map), written ONLY by global_load_lds.
__global__ __launch_bounds__(256, 1) void k_gemm_qkv(
    const u16* __restrict__ xb, const u16* __restrict__ wqb,
    const u16* __restrict__ wkb, const u16* __restrict__ wvb,
    const float* __restrict__ bq, const float* __restrict__ bk, const float* __restrict__ bv,
    u16* __restrict__ qout, u16* __restrict__ kout, u16* __restrict__ vtout) {
  __shared__ __align__(16) u16 sh[73728];
  const int tid = threadIdx.x;
  const int w = tid >> 6, lane = tid & 63, ln = lane & 31, hi = lane >> 5;
  const int wr = w >> 1, wc = w & 1;
  const int id = blockIdx.x;
  const float qscale = 0.12751744630098356f;  // log2(e)/sqrt(128)

  if (id < 128) {
    // ------------------------------ Q path: 256x256 tile, 4x4 acc per wave
    const int m0 = (id >> 3) * 256, n0 = (id & 7) * 256;
    const u16* Arow = xb + (size_t)m0 * 2048;
    const u16* Brow = wqb + (size_t)n0 * 2048;

    // staging: A 256 rows x 9 slots = 2304, B same -> 4608 slots of 16B
    // = 72 wave-slices, 4 waves x 18 each
    const u16* sb[18];
#pragma unroll
    for (int i = 0; i < 18; ++i) {
      int s = (w + i * 4) * 64 + lane;
      const u16* base; int r, c;
      if (s < 2304) { r = s / 9; c = s % 9; if (c > 7) c = 0; base = Arow; }
      else { int s2 = s - 2304; r = s2 / 9; c = s2 % 9; if (c > 7) c = 0; base = Brow; }
      sb[i] = base + (size_t)r * 2048 + c * 8;
    }

    f32x16 acc[4][4];
#pragma unroll
    for (int am = 0; am < 4; ++am)
#pragma unroll
      for (int an = 0; an < 4; ++an) acc[am][an] = zero16();

    int aoff[4], boff[4];
#pragma unroll
    for (int t = 0; t < 4; ++t) {
      aoff[t] = (wr * 128 + t * 32 + ln) * 72 + hi * 8;
      boff[t] = 18432 + (wc * 128 + t * 32 + ln) * 72 + hi * 8;
    }

    // prologue: stage tile 0 into buffer 0
#pragma unroll
    for (int i = 0; i < 18; ++i)
      cp16(sb[i], (void*)(sh + (w + i * 4) * 512));
    __syncthreads();

    for (int it = 0; it < 32; ++it) {
      const int cur = (it & 1) * 36864;
      const int nxt = 36864 - cur;
      const int k0n = (it < 31) ? (it + 1) * 64 : 0;
#pragma unroll
      for (int i = 0; i < 18; ++i)
        cp16(sb[i] + k0n, (void*)(sh + nxt + (w + i * 4) * 512));

#pragma unroll
      for (int kc = 0; kc < 4; ++kc) {
        const int ko = kc * 16;
        bf16x8 af[4], bfr[4];
#pragma unroll
        for (int t = 0; t < 4; ++t) {
          af[t]  = *(const bf16x8*)&sh[cur + aoff[t] + ko];
          bfr[t] = *(const bf16x8*)&sh[cur + boff[t] + ko];
        }
#pragma unroll
        for (int am = 0; am < 4; ++am)
#pragma unroll
          for (int an = 0; an < 4; ++an)
            acc[am][an] = MFMA32(af[am], bfr[an], acc[am][an]);
      }

      __syncthreads();  // drains own prefetch (vmcnt0) after compute
    }

    // epilogue; C/D: col = ln, row = (r&3) + 8*(r>>2) + 4*hi
#pragma unroll
    for (int am = 0; am < 4; ++am) {
      const int mbase = m0 + wr * 128 + am * 32;
#pragma unroll
      for (int an = 0; an < 4; ++an) {
        const int nloc = n0 + wc * 128 + an * 32 + ln;
        const float bsc = bq[nloc] * qscale;
        f32x16 a = acc[am][an];
#pragma unroll
        for (int r = 0; r < 16; ++r) {
          int row = (r & 3) + 8 * (r >> 2) + 4 * hi;
          qout[(size_t)(mbase + row) * 2048 + nloc] = f2bf(a[r] * qscale + bsc);
        }
      }
    }
    return;
  }

  // ------------------------------ K/V path: old verified 128x128 tile
  const int id2 = id - 128;
  const int mode = 1 + (id2 >> 5);  // 1=K, 2=V
  const int m0 = (id2 & 31) * 128;
  const u16* __restrict__ Bp = (mode == 1) ? wkb : wvb;
  const u16* Arow = xb + (size_t)m0 * 2048;
  const u16* Brow = Bp;

  // staging: A 128 rows x 9 slots = 1152, B same = 2304 slots
  // -> 36 wave-slices, 4 waves x 9 each
  const u16* sb[9];
#pragma unroll
  for (int i = 0; i < 9; ++i) {
    int s = (w + i * 4) * 64 + lane;
    const u16* base; int r, c;
    if (s < 1152) { r = s / 9; c = s % 9; if (c > 7) c = 0; base = Arow; }
    else { int s2 = s - 1152; r = s2 / 9; c = s2 % 9; if (c > 7) c = 0; base = Brow; }
    sb[i] = base + (size_t)r * 2048 + c * 8;
  }

  f32x16 acc[2][2];
  acc[0][0] = zero16(); acc[0][1] = zero16(); acc[1][0] = zero16(); acc[1][1] = zero16();

  const int a0off = (wr * 64 + ln) * 72 + hi * 8;
  const int b0off = 9216 + (wc * 64 + ln) * 72 + hi * 8;

#pragma unroll
  for (int i = 0; i < 9; ++i)
    cp16(sb[i], (void*)(sh + (w + i * 4) * 512));
  __syncthreads();

  for (int it = 0; it < 32; ++it) {
    const int cur = (it & 1) * 18432;
    const int nxt = 18432 - cur;
    const int k0n = (it < 31) ? (it + 1) * 64 : 0;
#pragma unroll
    for (int i = 0; i < 9; ++i)
      cp16(sb[i] + k0n, (void*)(sh + nxt + (w + i * 4) * 512));

#pragma unroll
    for (int kc = 0; kc < 4; ++kc) {
      const int ko = kc * 16;
      bf16x8 a0 = *(const bf16x8*)&sh[cur + a0off + ko];
      bf16x8 a1 = *(const bf16x8*)&sh[cur + a0off + 2304 + ko];
      bf16x8 b0 = *(const bf16x8*)&sh[cur + b0off + ko];
      bf16x8 b1 = *(const bf16x8*)&sh[cur + b0off + 2304 + ko];
      acc[0][0] = MFMA32(a0, b0, acc[0][0]);
      acc[0][1] = MFMA32(a0, b1, acc[0][1]);
      acc[1][0] = MFMA32(a1, b0, acc[1][0]);
      acc[1][1] = MFMA32(a1, b1, acc[1][1]);
    }

    __syncthreads();
  }

  // epilogue; C/D: col = ln, row = (r&3) + 8*(r>>2) + 4*hi
#pragma unroll
  for (int fm = 0; fm < 2; ++fm) {
#pragma unroll
    for (int fn = 0; fn < 2; ++fn) {
      f32x16 a = acc[fm][fn];
      const int mbase = m0 + wr * 64 + fm * 32;
      const int nloc = wc * 64 + fn * 32 + ln;
      if (mode == 1) {
        const float bb = bk[nloc];
#pragma unroll
        for (int r = 0; r < 16; ++r) {
          int row = (r & 3) + 8 * (r >> 2) + 4 * hi;
          kout[(size_t)(mbase + row) * 128 + nloc] = f2bf(a[r] + bb);
        }
      } else {
        const float bb = bv[nloc];
#pragma unroll
        for (int r = 0; r < 16; ++r) {
          int row = (r & 3) + 8 * (r >> 2) + 4 * hi;
          int m = mbase + row;
          vtout[(size_t)((m >> 11) * 128 + nloc) * 2048 + (m & 2047)] = f2bf(a[r] + bb);
        }
      }
    }
  }
}

// ------------------------------------------------------- K3: flash attention
// EXACT R8 (best measured 73.2us): grid (8 qtiles, 16 heads, 2 batch),
// 512 thr = 8 waves x 32 q each, BQ=256, BK=64, double-buffered LDS, ONE
// barrier per iter, 1 block/CU -> 2 waves/SIMD.
//  S^T = K_tile(A) x Q(B); O^T = V^T(A) x P^T(B).
// Fixed-max softmax (scores bounded ~|5|): p = exp2(s') with the log2e fold.
// LDS: 2 x (Ks[64][136] | Vts[128][72]) u16 = 71680 B, written ONLY by
// global_load_lds.
__global__ __launch_bounds__(512, 2) void k_attn(
    const u16* __restrict__ qb, const u16* __restrict__ kb, const u16* __restrict__ vtb,
    float* __restrict__ out) {
  __shared__ __align__(16) u16 sh[35840];
  const int tid = threadIdx.x;
  const int w = tid >> 6, lane = tid & 63, ln = lane & 31, hi = lane >> 5;
  const int q0 = blockIdx.x * 256, h = blockIdx.y, b = blockIdx.z;
  const size_t bL = (size_t)b * 2048;
  const u16* kbase = kb + bL * 128;
  const u16* vbase = vtb + (size_t)b * 128 * 2048;

  // persistent Q fragments, ONE 32-q block per wave (B-op: col = ln, k = kc*16+hi*8+j)
  bf16x8 qf[8];
  {
    const u16* qrow = qb + (bL + q0 + w * 32 + ln) * 2048 + h * 128 + hi * 8;
#pragma unroll
    for (int kc = 0; kc < 8; ++kc) qf[kc] = *(const bf16x8*)(qrow + kc * 16);
  }

  // staging: Ks 64 x 17 slots (16 data + 1 pad) = 1088, Vts 128 x 9 = 1152
  // -> 2240 slots = 35 wave-slices of 64 lanes x 16B, 8 waves: w<3 get 5, else 4
  const u16* sb[5]; int smul[5];
  const int nsl = (w < 3) ? 5 : 4;
#pragma unroll
  for (int i = 0; i < 5; ++i) {
    int sl = w + i * 8;
    if (sl < 35) {
      int s = sl * 64 + lane;
      if (s < 1088) {
        int r = s / 17, c = s % 17; if (c > 15) c = 0;
        sb[i] = kbase + r * 128 + c * 8; smul[i] = 128;
      } else {
        int s2 = s - 1088; int r = s2 / 9, c = s2 % 9; if (c > 7) c = 0;
        sb[i] = vbase + (size_t)r * 2048 + c * 8; smul[i] = 1;
      }
    } else { sb[i] = kbase; smul[i] = 0; }
  }

  // prologue: stage tile 0 into buffer 0
#pragma unroll
  for (int i = 0; i < 5; ++i)
    if (i < nsl) cp16(sb[i], (void*)(sh + (w + i * 8) * 512));
  __syncthreads();

  f32x16 o[4];
#pragma unroll
  for (int dg = 0; dg < 4; ++dg) o[dg] = zero16();
  float l = 0.f;

  const int kro = ln * 136 + hi * 8;        // Ks A-frag base (S^T: m = k')
  const int vro = 8704 + ln * 72 + hi * 8;  // Vts A-frag base (O^T: m = d)

  for (int it = 0; it < 32; ++it) {
    const int cur = (it & 1) * 17920;
    const int nxt = 17920 - cur;
    // prefetch next tile into the idle buffer (last iter: refetch tile 0 —
    // in-bounds, discarded; keeps all lanes issuing so the lane*16 map holds)
    const size_t k0n = (it < 31) ? (size_t)(it + 1) * 64 : 0;
#pragma unroll
    for (int i = 0; i < 5; ++i)
      if (i < nsl) cp16(sb[i] + k0n * smul[i], (void*)(sh + nxt + (w + i * 8) * 512));

    // S^T[k'][q] (Q pre-scaled by log2e/sqrt(hd)); two 32-k' blocks per wave
    f32x16 s0 = zero16(), s1 = zero16();
#pragma unroll
    for (int kc = 0; kc < 8; ++kc) {
      bf16x8 a0 = *(const bf16x8*)&sh[cur + kro + kc * 16];
      bf16x8 a1 = *(const bf16x8*)&sh[cur + kro + 32 * 136 + kc * 16];
      s0 = MFMA32(a0, qf[kc], s0);
      s1 = MFMA32(a1, qf[kc], s1);
    }

    // p = exp2(s') (fixed max), pack truncated-bf16 pairs via v_perm, sum l
    // from the SAME truncated values (ratio-consistent with PV).
    u32 pk[16];
#pragma unroll
    for (int i = 0; i < 8; ++i) {
      float a = fexp2(s0[2 * i]), c = fexp2(s0[2 * i + 1]);
      pk[i] = __builtin_amdgcn_perm(__builtin_bit_cast(u32, c),
                                    __builtin_bit_cast(u32, a), 0x07060302u);
      float d = fexp2(s1[2 * i]), e = fexp2(s1[2 * i + 1]);
      pk[8 + i] = __builtin_amdgcn_perm(__builtin_bit_cast(u32, e),
                                        __builtin_bit_cast(u32, d), 0x07060302u);
    }
#pragma unroll
    for (int i = 0; i < 16; ++i) {
      l += __builtin_bit_cast(float, pk[i] << 16);
      l += __builtin_bit_cast(float, pk[i] & 0xffff0000u);
    }

    // P^T B-frags: chunk c needs k' = 16c + 8hi + j (r4-verified mapping).
    bf16x8 pf[4];
#pragma unroll
    for (int c = 0; c < 4; ++c) {
      const int wb = 4 * c;
      u32 send0 = hi ? pk[wb] : pk[wb + 2];
      u32 send1 = hi ? pk[wb + 1] : pk[wb + 3];
      u32 r0 = (u32)__shfl_xor((int)send0, 32, 64);
      u32 r1 = (u32)__shfl_xor((int)send1, 32, 64);
      u32x4 v;
      v[0] = hi ? r0 : pk[wb];
      v[1] = hi ? r1 : pk[wb + 1];
      v[2] = hi ? pk[wb + 2] : r0;
      v[3] = hi ? pk[wb + 3] : r1;
      pf[c] = __builtin_bit_cast(bf16x8, v);
    }

    // O^T += V^T(A) x P^T(B)
#pragma unroll
    for (int c = 0; c < 4; ++c)
#pragma unroll
      for (int dg = 0; dg < 4; ++dg) {
        bf16x8 va = *(const bf16x8*)&sh[cur + vro + dg * 2304 + c * 16];
        o[dg] = MFMA32(va, pf[c], o[dg]);
      }

    __syncthreads();  // drains own prefetch (vmcnt0) after compute; joins waves
  }

  // combine l across the two k'-halves (lane ^ 32 holds the other rows)
  l += __shfl_xor(l, 32, 64);
  const float inv = 1.0f / l;

  // O^T: col = q = ln, row = d = dg*32 + (r&3) + 8*(r>>2) + 4*hi
  float* orow = out + (bL + q0 + w * 32 + ln) * 2048 + h * 128 + hi * 4;
#pragma unroll
  for (int dg = 0; dg < 4; ++dg)
#pragma unroll
    for (int rq = 0; rq < 4; ++rq) {
      float4 v4;
      v4.x = o[dg][rq * 4 + 0] * inv; v4.y = o[dg][rq * 4 + 1] * inv;
      v4.z = o[dg][rq * 4 + 2] * inv; v4.w = o[dg][rq * 4 + 3] * inv;
      *(float4*)&orow[dg * 32 + rq * 8] = v4;
    }
}

// ----------------------------------------------------------------- launcher
extern "C" void kernel_launch(void* const* d_in, const int* in_sizes, int n_in,
                              void* d_out, int out_size, void* d_ws, size_t ws_size,
                              hipStream_t stream) {
  const float* x  = (const float*)d_in[0];
  const float* wq = (const float*)d_in[1];
  const float* bq = (const float*)d_in[2];
  const float* wk = (const float*)d_in[3];
  const float* bk = (const float*)d_in[4];
  const float* wv = (const float*)d_in[5];
  const float* bv = (const float*)d_in[6];
  float* out = (float*)d_out;
  char* ws = (char*)d_ws;

  u16* xb   = (u16*)(ws);
  u16* wqb  = (u16*)(ws + 16777216);
  u16* wkb  = (u16*)(ws + 25165824);
  u16* wvb  = (u16*)(ws + 25690112);
  u16* qb   = (u16*)(ws + 26214400);
  u16* kbuf = (u16*)(ws + 42991616);
  u16* vtb  = (u16*)(ws + 44040192);

  k_convert<<<2048, 256, 0, stream>>>(x, wq, wk, wv, xb, wqb, wkb, wvb);
  k_gemm_qkv<<<192, 256, 0, stream>>>(xb, wqb, wkb, wvb, bq, bk, bv, qb, kbuf, vtb);
  k_attn<<<dim3(8, 16, 2), 512, 0, stream>>>(qb, kbuf, vtb, out);
}

// Round 9
// 231.423 us; speedup vs baseline: 1.0422x; 1.0422x over previous
//
#include <hip/hip_runtime.h>
#include <hip/hip_bf16.h>

// MQA fused pipeline, bf16 MFMA (32x32x16), fp32 accumulate.
// B=2, L=2048, D_MODEL=2048, H=16, HD=128.
// HARNESS DTYPES (established r1-r3): inputs fp32, OUTPUT fp32
// (threshold bf16-calibrated 3.6e-3).
//
// R14 post-mortem (FAILED, 241.2): 256^2 Q-tiles -> only 192 blocks on 256
// CUs (quarter of GPU idle) + 1 wave/SIMD. Constraint algebra: 2 blocks/CU
// forces BM+BN<=284 (128^2 max); ratio-2 wave tiles force 256 acc VGPR ->
// 1 wave/SIMD. The round-2 gemm IS the constrained optimum of this family.
// Session: best total = ROUND 2 = 229.5us (gemm BK=64/128^2 1-barrier dbuf,
// attn R8 512thr). Six structural experiments since (R9-R14) all <= it.
// R15: REVERT to round-2 exact + one strictly-safe micro-fix: the last-iter
// dummy prefetch (tile-0 refetch) in gemm and attn is replaced by a
// wave-UNIFORM `if (it<31)` skip — all-or-nothing branch, lane*16 map
// unaffected; drops one staging round + final vmcnt drain per kernel tail.
// Predicted: total ~228-233; attn ~73-77 (MfmaUtil ~39); gemm below attn.
//
// ws layout (bytes):
//   xb   @ 0         : x   bf16 [4096][2048]   16777216
//   wqb  @ 16777216  : Wq  bf16 [2048][2048]    8388608
//   wkb  @ 25165824  : Wk  bf16 [128][2048]      524288
//   wvb  @ 25690112  : Wv  bf16 [128][2048]      524288
//   qb   @ 26214400  : Q   bf16 [4096][2048]   16777216  (pre-scaled log2e/sqrt(128))
//   kbuf @ 42991616  : K   bf16 [4096][128]     1048576
//   vtb  @ 44040192  : V^T bf16 [2][128][2048]  1048576
// total 45088768

typedef unsigned short u16;
typedef unsigned int u32;
typedef __bf16 bf16x8 __attribute__((ext_vector_type(8)));
typedef float f32x16 __attribute__((ext_vector_type(16)));
typedef u16 u16x4 __attribute__((ext_vector_type(4)));
typedef u32 u32x4 __attribute__((ext_vector_type(4)));

#define MFMA32(a, b, c) __builtin_amdgcn_mfma_f32_32x32x16_bf16((a), (b), (c), 0, 0, 0)

__device__ __forceinline__ u16 f2bf(float f) {
  __hip_bfloat16 h = __float2bfloat16(f);
  return __builtin_bit_cast(u16, h);
}

__device__ __forceinline__ float fexp2(float x) {
#if __has_builtin(__builtin_amdgcn_exp2f)
  return __builtin_amdgcn_exp2f(x);
#else
  return exp2f(x);
#endif
}

// async global->LDS, 16B per lane; LDS dest = wave-uniform base + lane*16
__device__ __forceinline__ void cp16(const void* g, void* l) {
  __builtin_amdgcn_global_load_lds(
      (const __attribute__((address_space(1))) u32*)g,
      (__attribute__((address_space(3))) u32*)l, 16, 0, 0);
}

__device__ __forceinline__ f32x16 zero16() {
  f32x16 v;
#pragma unroll
  for (int i = 0; i < 16; ++i) v[i] = 0.f;
  return v;
}

// ---------------------------------------------------------------- K1: convert
__global__ __launch_bounds__(256) void k_convert(
    const float* __restrict__ x, const float* __restrict__ wq,
    const float* __restrict__ wk, const float* __restrict__ wv,
    u16* __restrict__ xb, u16* __restrict__ wqb,
    u16* __restrict__ wkb, u16* __restrict__ wvb) {
  int idx = blockIdx.x * 256 + threadIdx.x;
  // float4 counts: x 2097152 | wq 1048576 | wk 65536 | wv 65536 = 3276800
  for (int i = idx; i < 3276800; i += 524288) {
    float4 v; u16* dst;
    if (i < 2097152) {
      v = ((const float4*)x)[i]; dst = xb + (size_t)i * 4;
    } else if (i < 3145728) {
      int j = i - 2097152; v = ((const float4*)wq)[j]; dst = wqb + (size_t)j * 4;
    } else if (i < 3211264) {
      int j = i - 3145728; v = ((const float4*)wk)[j]; dst = wkb + (size_t)j * 4;
    } else {
      int j = i - 3211264; v = ((const float4*)wv)[j]; dst = wvb + (size_t)j * 4;
    }
    u16x4 o;
    o[0] = f2bf(v.x); o[1] = f2bf(v.y); o[2] = f2bf(v.z); o[3] = f2bf(v.w);
    *(u16x4*)dst = o;
  }
}

// ------------------------------------------------- K2: Q and K/V^T projections
// grid (32, 18): y<16 -> Q col-blocks, y==16 -> K, y==17 -> V. 128x128 tile,
// BK=64, double-buffered LDS, ONE barrier per iter (round-2 schedule).
// LDS per buffer: As[128][72] | Bs[128][72] u16 (rows = 8 data slots + 1 pad
// slot of 16B; pad slots included in the async-copy slot map so the
// contiguous lane*16 layout matches). 2 buffers = 73728 B -> 2 blocks/CU.
__global__ __launch_bounds__(256, 2) void k_gemm_qkv(
    const u16* __restrict__ xb, const u16* __restrict__ wqb,
    const u16* __restrict__ wkb, const u16* __restrict__ wvb,
    const float* __restrict__ bq, const float* __restrict__ bk, const float* __restrict__ bv,
    u16* __restrict__ qout, u16* __restrict__ kout, u16* __restrict__ vtout) {
  __shared__ __align__(16) u16 sh[36864];
  const int tid = threadIdx.x;
  const int w = tid >> 6, lane = tid & 63, ln = lane & 31, hi = lane >> 5;
  const int wr = w >> 1, wc = w & 1;
  const int m0 = blockIdx.x * 128;
  const int by = blockIdx.y;
  const int mode = (by < 16) ? 0 : (by - 15);  // 0=Q, 1=K, 2=V (block-uniform)
  const int n0loc = (mode == 0) ? by * 128 : 0;
  const u16* __restrict__ Bp = (mode == 0) ? wqb : (mode == 1 ? wkb : wvb);
  const u16* Arow = xb + (size_t)m0 * 2048;
  const u16* Brow = Bp + (size_t)n0loc * 2048;

  // staging: A 128 rows x 9 slots = 1152, B same = 2304 slots of 16B
  // -> 36 wave-slices of 64 lanes, 4 waves x 9 slices each
  const u16* sb[9];
#pragma unroll
  for (int i = 0; i < 9; ++i) {
    int s = (w + i * 4) * 64 + lane;
    const u16* base; int r, c;
    if (s < 1152) { r = s / 9; c = s % 9; if (c > 7) c = 0; base = Arow; }
    else { int s2 = s - 1152; r = s2 / 9; c = s2 % 9; if (c > 7) c = 0; base = Brow; }
    sb[i] = base + (size_t)r * 2048 + c * 8;
  }

  f32x16 acc[2][2];
  acc[0][0] = zero16(); acc[0][1] = zero16(); acc[1][0] = zero16(); acc[1][1] = zero16();

  const int a0off = (wr * 64 + ln) * 72 + hi * 8;           // A-frag base (u16)
  const int b0off = 9216 + (wc * 64 + ln) * 72 + hi * 8;    // B-frag base (u16)

  // prologue: stage tile 0 into buffer 0
#pragma unroll
  for (int i = 0; i < 9; ++i)
    cp16(sb[i], (void*)(sh + (w + i * 4) * 512));
  __syncthreads();

  for (int it = 0; it < 32; ++it) {
    const int cur = (it & 1) * 18432;
    const int nxt = 18432 - cur;
    // prefetch next K-tile into the idle buffer. Last iter: SKIP (wave-uniform
    // branch — all lanes or none, so the lane*16 async-copy map is unaffected;
    // saves one staging round + its vmcnt drain on the final barrier).
    if (it < 31) {
      const int k0n = (it + 1) * 64;
#pragma unroll
      for (int i = 0; i < 9; ++i)
        cp16(sb[i] + k0n, (void*)(sh + nxt + (w + i * 4) * 512));
    }

#pragma unroll
    for (int kc = 0; kc < 4; ++kc) {
      const int ko = kc * 16;
      bf16x8 a0 = *(const bf16x8*)&sh[cur + a0off + ko];
      bf16x8 a1 = *(const bf16x8*)&sh[cur + a0off + 2304 + ko];
      bf16x8 b0 = *(const bf16x8*)&sh[cur + b0off + ko];
      bf16x8 b1 = *(const bf16x8*)&sh[cur + b0off + 2304 + ko];
      acc[0][0] = MFMA32(a0, b0, acc[0][0]);
      acc[0][1] = MFMA32(a0, b1, acc[0][1]);
      acc[1][0] = MFMA32(a1, b0, acc[1][0]);
      acc[1][1] = MFMA32(a1, b1, acc[1][1]);
    }

    __syncthreads();  // drains own prefetch (vmcnt0) after compute; joins waves
  }

  // epilogue; C/D layout: col = lane&31, row = (r&3) + 8*(r>>2) + 4*(lane>>5)
  // qscale = log2(e)/sqrt(128): folds both the softmax scale AND the exp->exp2
  // conversion into Q (exact: bias is inside Q before the K dot product).
  const float qscale = 0.12751744630098356f;
#pragma unroll
  for (int fm = 0; fm < 2; ++fm) {
#pragma unroll
    for (int fn = 0; fn < 2; ++fn) {
      f32x16 a = acc[fm][fn];
      const int mbase = m0 + wr * 64 + fm * 32;
      const int nloc = n0loc + wc * 64 + fn * 32 + ln;
      if (mode == 0) {
        const float bsc = bq[nloc] * qscale;
#pragma unroll
        for (int r = 0; r < 16; ++r) {
          int row = (r & 3) + 8 * (r >> 2) + 4 * hi;
          qout[(size_t)(mbase + row) * 2048 + nloc] = f2bf(a[r] * qscale + bsc);
        }
      } else if (mode == 1) {
        const float bb = bk[nloc];
#pragma unroll
        for (int r = 0; r < 16; ++r) {
          int row = (r & 3) + 8 * (r >> 2) + 4 * hi;
          kout[(size_t)(mbase + row) * 128 + nloc] = f2bf(a[r] + bb);
        }
      } else {
        const float bb = bv[nloc];
#pragma unroll
        for (int r = 0; r < 16; ++r) {
          int row = (r & 3) + 8 * (r >> 2) + 4 * hi;
          int m = mbase + row;
          vtout[(size_t)((m >> 11) * 128 + nloc) * 2048 + (m & 2047)] = f2bf(a[r] + bb);
        }
      }
    }
  }
}

// ------------------------------------------------------- K3: flash attention
// EXACT round-2 structure (best measured 73.2us): grid (8 qtiles, 16 heads,
// 2 batch), 512 thr = 8 waves x 32 q each, BQ=256, BK=64, double-buffered
// LDS, ONE barrier per iter, 1 block/CU -> 2 waves/SIMD.
//  S^T = K_tile(A) x Q(B); O^T = V^T(A) x P^T(B).
// Fixed-max softmax (scores bounded ~|5|): p = exp2(s') with the log2e fold.
// LDS: 2 x (Ks[64][136] | Vts[128][72]) u16 = 71680 B, written ONLY by
// global_load_lds. Only change vs round-2: last-iter prefetch skipped via
// wave-uniform branch (safe; saves one staging round + final drain).
__global__ __launch_bounds__(512, 2) void k_attn(
    const u16* __restrict__ qb, const u16* __restrict__ kb, const u16* __restrict__ vtb,
    float* __restrict__ out) {
  __shared__ __align__(16) u16 sh[35840];
  const int tid = threadIdx.x;
  const int w = tid >> 6, lane = tid & 63, ln = lane & 31, hi = lane >> 5;
  const int q0 = blockIdx.x * 256, h = blockIdx.y, b = blockIdx.z;
  const size_t bL = (size_t)b * 2048;
  const u16* kbase = kb + bL * 128;
  const u16* vbase = vtb + (size_t)b * 128 * 2048;

  // persistent Q fragments, ONE 32-q block per wave (B-op: col = ln, k = kc*16+hi*8+j)
  bf16x8 qf[8];
  {
    const u16* qrow = qb + (bL + q0 + w * 32 + ln) * 2048 + h * 128 + hi * 8;
#pragma unroll
    for (int kc = 0; kc < 8; ++kc) qf[kc] = *(const bf16x8*)(qrow + kc * 16);
  }

  // staging: Ks 64 x 17 slots (16 data + 1 pad) = 1088, Vts 128 x 9 = 1152
  // -> 2240 slots = 35 wave-slices of 64 lanes x 16B, 8 waves: w<3 get 5, else 4
  const u16* sb[5]; int smul[5];
  const int nsl = (w < 3) ? 5 : 4;
#pragma unroll
  for (int i = 0; i < 5; ++i) {
    int sl = w + i * 8;
    if (sl < 35) {
      int s = sl * 64 + lane;
      if (s < 1088) {
        int r = s / 17, c = s % 17; if (c > 15) c = 0;
        sb[i] = kbase + r * 128 + c * 8; smul[i] = 128;
      } else {
        int s2 = s - 1088; int r = s2 / 9, c = s2 % 9; if (c > 7) c = 0;
        sb[i] = vbase + (size_t)r * 2048 + c * 8; smul[i] = 1;
      }
    } else { sb[i] = kbase; smul[i] = 0; }
  }

  // prologue: stage tile 0 into buffer 0
#pragma unroll
  for (int i = 0; i < 5; ++i)
    if (i < nsl) cp16(sb[i], (void*)(sh + (w + i * 8) * 512));
  __syncthreads();

  f32x16 o[4];
#pragma unroll
  for (int dg = 0; dg < 4; ++dg) o[dg] = zero16();
  float l = 0.f;

  const int kro = ln * 136 + hi * 8;        // Ks A-frag base (S^T: m = k')
  const int vro = 8704 + ln * 72 + hi * 8;  // Vts A-frag base (O^T: m = d)

  for (int it = 0; it < 32; ++it) {
    const int cur = (it & 1) * 17920;
    const int nxt = 17920 - cur;
    // prefetch next tile into the idle buffer. Last iter: SKIP (wave-uniform).
    if (it < 31) {
      const size_t k0n = (size_t)(it + 1) * 64;
#pragma unroll
      for (int i = 0; i < 5; ++i)
        if (i < nsl) cp16(sb[i] + k0n * smul[i], (void*)(sh + nxt + (w + i * 8) * 512));
    }

    // S^T[k'][q] (Q pre-scaled by log2e/sqrt(hd)); two 32-k' blocks per wave
    f32x16 s0 = zero16(), s1 = zero16();
#pragma unroll
    for (int kc = 0; kc < 8; ++kc) {
      bf16x8 a0 = *(const bf16x8*)&sh[cur + kro + kc * 16];
      bf16x8 a1 = *(const bf16x8*)&sh[cur + kro + 32 * 136 + kc * 16];
      s0 = MFMA32(a0, qf[kc], s0);
      s1 = MFMA32(a1, qf[kc], s1);
    }

    // p = exp2(s') (fixed max), pack truncated-bf16 pairs via v_perm, sum l
    // from the SAME truncated values (ratio-consistent with PV).
    u32 pk[16];
#pragma unroll
    for (int i = 0; i < 8; ++i) {
      float a = fexp2(s0[2 * i]), c = fexp2(s0[2 * i + 1]);
      pk[i] = __builtin_amdgcn_perm(__builtin_bit_cast(u32, c),
                                    __builtin_bit_cast(u32, a), 0x07060302u);
      float d = fexp2(s1[2 * i]), e = fexp2(s1[2 * i + 1]);
      pk[8 + i] = __builtin_amdgcn_perm(__builtin_bit_cast(u32, e),
                                        __builtin_bit_cast(u32, d), 0x07060302u);
    }
#pragma unroll
    for (int i = 0; i < 16; ++i) {
      l += __builtin_bit_cast(float, pk[i] << 16);
      l += __builtin_bit_cast(float, pk[i] & 0xffff0000u);
    }

    // P^T B-frags: chunk c needs k' = 16c + 8hi + j (r4-verified mapping).
    bf16x8 pf[4];
#pragma unroll
    for (int c = 0; c < 4; ++c) {
      const int wb = 4 * c;
      u32 send0 = hi ? pk[wb] : pk[wb + 2];
      u32 send1 = hi ? pk[wb + 1] : pk[wb + 3];
      u32 r0 = (u32)__shfl_xor((int)send0, 32, 64);
      u32 r1 = (u32)__shfl_xor((int)send1, 32, 64);
      u32x4 v;
      v[0] = hi ? r0 : pk[wb];
      v[1] = hi ? r1 : pk[wb + 1];
      v[2] = hi ? pk[wb + 2] : r0;
      v[3] = hi ? pk[wb + 3] : r1;
      pf[c] = __builtin_bit_cast(bf16x8, v);
    }

    // O^T += V^T(A) x P^T(B)
#pragma unroll
    for (int c = 0; c < 4; ++c)
#pragma unroll
      for (int dg = 0; dg < 4; ++dg) {
        bf16x8 va = *(const bf16x8*)&sh[cur + vro + dg * 2304 + c * 16];
        o[dg] = MFMA32(va, pf[c], o[dg]);
      }

    __syncthreads();  // drains own prefetch (vmcnt0) after compute; joins waves
  }

  // combine l across the two k'-halves (lane ^ 32 holds the other rows)
  l += __shfl_xor(l, 32, 64);
  const float inv = 1.0f / l;

  // O^T: col = q = ln, row = d = dg*32 + (r&3) + 8*(r>>2) + 4*hi
  float* orow = out + (bL + q0 + w * 32 + ln) * 2048 + h * 128 + hi * 4;
#pragma unroll
  for (int dg = 0; dg < 4; ++dg)
#pragma unroll
    for (int rq = 0; rq < 4; ++rq) {
      float4 v4;
      v4.x = o[dg][rq * 4 + 0] * inv; v4.y = o[dg][rq * 4 + 1] * inv;
      v4.z = o[dg][rq * 4 + 2] * inv; v4.w = o[dg][rq * 4 + 3] * inv;
      *(float4*)&orow[dg * 32 + rq * 8] = v4;
    }
}

// ----------------------------------------------------------------- launcher
extern "C" void kernel_launch(void* const* d_in, const int* in_sizes, int n_in,
                              void* d_out, int out_size, void* d_ws, size_t ws_size,
                              hipStream_t stream) {
  const float* x  = (const float*)d_in[0];
  const float* wq = (const float*)d_in[1];
  const float* bq = (const float*)d_in[2];
  const float* wk = (const float*)d_in[3];
  const float* bk = (const float*)d_in[4];
  const float* wv = (const float*)d_in[5];
  const float* bv = (const float*)d_in[6];
  float* out = (float*)d_out;
  char* ws = (char*)d_ws;

  u16* xb   = (u16*)(ws);
  u16* wqb  = (u16*)(ws + 16777216);
  u16* wkb  = (u16*)(ws + 25165824);
  u16* wvb  = (u16*)(ws + 25690112);
  u16* qb   = (u16*)(ws + 26214400);
  u16* kbuf = (u16*)(ws + 42991616);
  u16* vtb  = (u16*)(ws + 44040192);

  k_convert<<<2048, 256, 0, stream>>>(x, wq, wk, wv, xb, wqb, wkb, wvb);
  k_gemm_qkv<<<dim3(32, 18), 256, 0, stream>>>(xb, wqb, wkb, wvb, bq, bk, bv, qb, kbuf, vtb);
  k_attn<<<dim3(8, 16, 2), 512, 0, stream>>>(qb, kbuf, vtb, out);
}